// Round 6
// baseline (1868.843 us; speedup 1.0000x reference)
//
#include <hip/hip_runtime.h>

typedef unsigned short u16;
typedef unsigned int u32;
typedef __attribute__((ext_vector_type(8))) short bf16x8;
typedef __attribute__((ext_vector_type(4))) float f32x4;

#define N_NODES 20000
#define N_EDGES 160000
#define DDIM    1000
#define KP      1024            // padded K / row stride (elements)
#define SP      41200000        // node-buffer spacing (bytes): 20096 rows + slack

__device__ __forceinline__ float b2f(u16 u) {
    union { u32 i; float f; } v; v.i = ((u32)u) << 16; return v.f;
}
__device__ __forceinline__ u16 f2b(float f) {
    union { float f; u32 i; } v; v.f = f;
    u32 r = v.i + 0x7FFFu + ((v.i >> 16) & 1u);
    return (u16)(r >> 16);
}
__device__ __forceinline__ u32 pack2(float a, float b) {
    return (u32)f2b(a) | ((u32)f2b(b) << 16);
}
__device__ __forceinline__ f32x4 mfma16(bf16x8 a, bf16x8 b, f32x4 c) {
    return __builtin_amdgcn_mfma_f32_16x16x32_bf16(a, b, c, 0, 0, 0);
}
__device__ __forceinline__ float sigmoidf_(float x) { return 1.0f / (1.0f + expf(-x)); }

// async global->LDS DMA, 16 B per lane; lds dest = wave-uniform base + lane*16
__device__ __forceinline__ void gl2lds16(const u16* g, u16* l) {
    __builtin_amdgcn_global_load_lds(
        (const __attribute__((address_space(1))) u32*)g,
        (__attribute__((address_space(3))) u32*)l, 16, 0, 0);
}

// ---------------------------------------------------------------------------
// fp32 [rows][1000] -> bf16 [rows][1024], zero-padded cols. One block per row.
// ---------------------------------------------------------------------------
__global__ __launch_bounds__(256) void cvt_rows(const float* __restrict__ in,
                                                u16* __restrict__ out) {
    int r = blockIdx.x, c = threadIdx.x * 4;
    u32 o[2] = {0, 0};
    if (c < DDIM) {
        float4 v = *(const float4*)(in + (size_t)r * DDIM + c);
        o[0] = pack2(v.x, v.y); o[1] = pack2(v.z, v.w);
    }
    *(uint2*)(out + (size_t)r * KP + c) = *(const uint2*)o;
}

// ---------------------------------------------------------------------------
// Stacked GRU weights: wcat[g][n][0:1024) = wih[g*1000+n][:], zero-pad;
//                      wcat[g][n][1024:2048) = whh[g*1000+n][:], zero-pad.
// One block per (g*1000+n) row, g=r/1000.
// ---------------------------------------------------------------------------
__global__ __launch_bounds__(256) void cvt_wcat(const float* __restrict__ wih,
                                                const float* __restrict__ whh,
                                                u16* __restrict__ wcat) {
    int r = blockIdx.x;                  // 0..2999
    int g = r / 1000, n = r - g * 1000;
    int c = threadIdx.x * 4;             // 0..1020
    u16* dst = wcat + ((size_t)g * 1024 + n) * 2048;
    u32 o[2] = {0, 0};
    if (c < DDIM) {
        float4 v = *(const float4*)(wih + (size_t)r * DDIM + c);
        o[0] = pack2(v.x, v.y); o[1] = pack2(v.z, v.w);
    }
    *(uint2*)(dst + c) = *(const uint2*)o;
    o[0] = 0; o[1] = 0;
    if (c < DDIM) {
        float4 v = *(const float4*)(whh + (size_t)r * DDIM + c);
        o[0] = pack2(v.x, v.y); o[1] = pack2(v.z, v.w);
    }
    *(uint2*)(dst + 1024 + c) = *(const uint2*)o;
}

// ---------------------------------------------------------------------------
// weight[l] fp32 [k<1000][n<1000] -> Wt bf16 [n<1024][k<1024], zero-padded.
// ---------------------------------------------------------------------------
__global__ __launch_bounds__(256) void transpose_w(const float* __restrict__ W,
                                                   u16* __restrict__ Wt) {
    __shared__ u16 t[32][33];
    int l = blockIdx.z;
    int nb = blockIdx.x * 32, kb = blockIdx.y * 32;
    int x = threadIdx.x, y = threadIdx.y;   // block (32, 8)
    const float* Wl = W + (size_t)l * 1000000;
    u16* Wtl = Wt + (size_t)l * (KP * KP);
    for (int i = 0; i < 32; i += 8) {
        int k = kb + y + i, n = nb + x;
        t[y + i][x] = (k < DDIM && n < DDIM) ? f2b(Wl[(size_t)k * DDIM + n]) : (u16)0;
    }
    __syncthreads();
    for (int i = 0; i < 32; i += 8) {
        int n = nb + y + i, k = kb + x;
        Wtl[(size_t)n * KP + k] = t[x][y + i];
    }
}

// ---------------------------------------------------------------------------
// CSR build (edge list constant): count -> scan -> fill
// ---------------------------------------------------------------------------
__global__ __launch_bounds__(256) void count_edges(const int* __restrict__ ei,
                                                   int* __restrict__ cnt) {
    int e = blockIdx.x * 256 + threadIdx.x;
    if (e < N_EDGES) atomicAdd(&cnt[ei[N_EDGES + e]], 1);
}

__global__ __launch_bounds__(1024) void scan_offsets(const int* __restrict__ cnt,
                                                     int* __restrict__ ofs) {
    __shared__ int s[1024];
    const int CH = 20;
    int t = threadIdx.x;
    int base = t * CH;
    int loc[CH];
    int sum = 0;
    for (int j = 0; j < CH; j++) {
        int i = base + j;
        loc[j] = sum;
        sum += (i < N_NODES) ? cnt[i] : 0;
    }
    s[t] = sum;
    __syncthreads();
    for (int d = 1; d < 1024; d <<= 1) {
        int v = (t >= d) ? s[t - d] : 0;
        __syncthreads();
        s[t] += v;
        __syncthreads();
    }
    int excl = s[t] - sum;
    for (int j = 0; j < CH; j++) {
        int i = base + j;
        if (i < N_NODES) ofs[i] = excl + loc[j];
    }
    if (t == 0) ofs[N_NODES] = N_EDGES;
}

__global__ __launch_bounds__(256) void fill_buckets(const int* __restrict__ ei,
                                                    const int* __restrict__ ofs,
                                                    int* __restrict__ cur,
                                                    int* __restrict__ bkt) {
    int e = blockIdx.x * 256 + threadIdx.x;
    if (e >= N_EDGES) return;
    int d = ei[N_EDGES + e];
    int pos = atomicAdd(&cur[d], 1);
    bkt[ofs[d] + pos] = e;
}

// ---------------------------------------------------------------------------
// agg[node] = sum_{e: dst=node} m[src(e)] * ew[e] — one block/node, no atomics
// ---------------------------------------------------------------------------
__global__ __launch_bounds__(256) void node_agg(const int* __restrict__ ei,
                                                const float* __restrict__ ew,
                                                const int* __restrict__ ofs,
                                                const int* __restrict__ bkt,
                                                const u16* __restrict__ m,
                                                u16* __restrict__ agg) {
    __shared__ int   s_src[64];
    __shared__ float s_w[64];
    int node = blockIdx.x;
    int t = threadIdx.x;                 // t<250 owns features [4t, 4t+4)
    int beg = ofs[node], end = ofs[node + 1];
    float4 acc = {0.f, 0.f, 0.f, 0.f};
    for (int cb = beg; cb < end; cb += 64) {
        int n = min(64, end - cb);
        if (t < n) {
            int e = bkt[cb + t];
            s_src[t] = ei[e];
            s_w[t]   = ew[e];
        }
        __syncthreads();
        if (t < 250) {
            for (int j = 0; j < n; j++) {
                int src = s_src[j];
                float w = s_w[j];
                uint2 v = *(const uint2*)(m + (size_t)src * KP + t * 4);
                const u16* p = (const u16*)&v;
                acc.x += b2f(p[0]) * w;
                acc.y += b2f(p[1]) * w;
                acc.z += b2f(p[2]) * w;
                acc.w += b2f(p[3]) * w;
            }
        }
        __syncthreads();
    }
    if (t < 250) {
        u32 o[2] = {pack2(acc.x, acc.y), pack2(acc.z, acc.w)};
        *(uint2*)(agg + (size_t)node * KP + t * 4) = *(const uint2*)o;
    }
}

// ---------------------------------------------------------------------------
// C[m<20000][n<1000] = A[m][k<1024] @ Bt[n][k<1024]^T  (all bf16, fp32 acc)
// m97 structure: 128x128 tile, BK=32, global_load_lds(16B), unpadded LDS.
// ---------------------------------------------------------------------------
__global__ __launch_bounds__(256) void gemm_bt(const u16* __restrict__ A,
                                               const u16* __restrict__ Bt,
                                               u16* __restrict__ C) {
    __shared__ u16 S[8192];              // Sa [128][32] @0, Sb [128][32] @4096
    int tid = threadIdx.x;
    int lane = tid & 63, wave = tid >> 6;
    int wr = wave >> 1, wc = wave & 1;
    int bid = blockIdx.x;
    int m0 = (bid >> 3) * 128, n0 = (bid & 7) * 128;

    const u16* pa0 = A  + (size_t)(m0 + (tid >> 2)) * KP + (tid & 3) * 8;
    const u16* pa1 = pa0 + (size_t)64 * KP;
    const u16* pb0 = Bt + (size_t)(n0 + (tid >> 2)) * KP + (tid & 3) * 8;
    const u16* pb1 = pb0 + (size_t)64 * KP;
    int su = wave * 512;                 // wave-uniform LDS chunk base (u16)
    f32x4 acc[4][4] = {};
    int fr = lane & 15, q = lane >> 4;

    for (int k0 = 0; k0 < KP; k0 += 32) {
        gl2lds16(pa0, &S[su]);
        gl2lds16(pa1, &S[su + 2048]);
        gl2lds16(pb0, &S[4096 + su]);
        gl2lds16(pb1, &S[4096 + su + 2048]);
        pa0 += 32; pa1 += 32; pb0 += 32; pb1 += 32;
        __syncthreads();
        bf16x8 af[4], bf[4];
#pragma unroll
        for (int i = 0; i < 4; i++)
            af[i] = *(const bf16x8*)&S[(wr * 64 + i * 16 + fr) * 32 + q * 8];
#pragma unroll
        for (int j = 0; j < 4; j++)
            bf[j] = *(const bf16x8*)&S[4096 + (wc * 64 + j * 16 + fr) * 32 + q * 8];
#pragma unroll
        for (int i = 0; i < 4; i++)
#pragma unroll
            for (int j = 0; j < 4; j++)
                acc[i][j] = mfma16(af[i], bf[j], acc[i][j]);
        __syncthreads();
    }

    int cc = lane & 15, r4 = q * 4;
#pragma unroll
    for (int i = 0; i < 4; i++)
#pragma unroll
        for (int j = 0; j < 4; j++) {
            int gn = n0 + wc * 64 + j * 16 + cc;
            if (gn >= DDIM) continue;
#pragma unroll
            for (int r = 0; r < 4; r++) {
                int gm = m0 + wr * 64 + i * 16 + r4 + r;
                if (gm < N_NODES) C[(size_t)gm * KP + gn] = f2b(acc[i][j][r]);
            }
        }
}

// ---------------------------------------------------------------------------
// Fused GRU, stacked-K: gates r,z accumulate over K=2048 = [agg | h];
// i_n over first half, h_n over second half. Tile 64 rows x 64 gate-cols.
// wcat = [3][1024][2048] (slab 0=r,1=z,2=n; cols 0:1024=w_ih, 1024:2048=w_hh).
// LDS 16 KB: A[64][32]@0, W[g][64][32]@2048+g*2048 (u16 idx). acc=64 f32/thr.
// ---------------------------------------------------------------------------
__global__ __launch_bounds__(256) void gru_fused(const u16* __restrict__ agg,
                                                 const u16* __restrict__ h,
                                                 const u16* __restrict__ wcat,
                                                 const float* __restrict__ bih,
                                                 const float* __restrict__ bhh,
                                                 u16* __restrict__ hout) {
    __shared__ u16 S[8192];
    int tid = threadIdx.x;
    int lane = tid & 63, wave = tid >> 6;
    int wr = wave >> 1, wc = wave & 1;

    int bid = blockIdx.x;                 // grid 5008 = 2*313 m-strips x 8 xcd
    int xcd = bid & 7;
    int s = bid >> 3;                     // 0..625
    int hi = (s >= 313) ? 1 : 0;
    int m0 = (s - hi * 313) * 64;
    int n0 = (xcd * 2 + hi) * 64;

    const u16* pa  = agg  + (size_t)(m0 + (tid >> 2)) * KP + (tid & 3) * 8;
    const u16* ph  = h    + (size_t)(m0 + (tid >> 2)) * KP + (tid & 3) * 8;
    const u16* pw0 = wcat + (size_t)(n0 + (tid >> 2)) * 2048 + (tid & 3) * 8;
    const u16* pw1 = pw0 + (size_t)1024 * 2048;
    const u16* pw2 = pw1 + (size_t)1024 * 2048;
    int su = wave * 512;                  // wave-uniform u16 base (byte = tid*16)

    f32x4 aR[2][2] = {}, aZ[2][2] = {}, aN[2][2] = {}, aH[2][2] = {};
    int fr = lane & 15, q = lane >> 4;

#define GRU_PHASE(PTR, AN)                                                    \
    for (int kk = 0; kk < 32; kk++) {                                         \
        gl2lds16(PTR, &S[su]);                                                \
        gl2lds16(pw0, &S[2048 + su]);                                         \
        gl2lds16(pw1, &S[4096 + su]);                                         \
        gl2lds16(pw2, &S[6144 + su]);                                         \
        PTR += 32; pw0 += 32; pw1 += 32; pw2 += 32;                           \
        __syncthreads();                                                      \
        bf16x8 aa[2], w0[2], w1[2], w2[2];                                    \
        _Pragma("unroll")                                                     \
        for (int i = 0; i < 2; i++) {                                         \
            int ra = (wr * 32 + i * 16 + fr) * 32 + q * 8;                    \
            int rb = (wc * 32 + i * 16 + fr) * 32 + q * 8;                    \
            aa[i] = *(const bf16x8*)&S[ra];                                   \
            w0[i] = *(const bf16x8*)&S[2048 + rb];                            \
            w1[i] = *(const bf16x8*)&S[4096 + rb];                            \
            w2[i] = *(const bf16x8*)&S[6144 + rb];                            \
        }                                                                     \
        _Pragma("unroll")                                                     \
        for (int i = 0; i < 2; i++)                                           \
            _Pragma("unroll")                                                 \
            for (int j = 0; j < 2; j++) {                                     \
                aR[i][j] = mfma16(aa[i], w0[j], aR[i][j]);                    \
                aZ[i][j] = mfma16(aa[i], w1[j], aZ[i][j]);                    \
                AN[i][j] = mfma16(aa[i], w2[j], AN[i][j]);                    \
            }                                                                 \
        __syncthreads();                                                      \
    }

    GRU_PHASE(pa, aN)     // k 0..1023:   agg vs w_ih -> r, z, i_n
    GRU_PHASE(ph, aH)     // k 1024..2047: h  vs w_hh -> r, z, h_n
#undef GRU_PHASE

    int cc = lane & 15, r4 = q * 4;
#pragma unroll
    for (int j = 0; j < 2; j++) {
        int gn = n0 + wc * 32 + j * 16 + cc;
        if (gn >= DDIM) continue;
        float br  = bih[gn] + bhh[gn];
        float bz  = bih[1000 + gn] + bhh[1000 + gn];
        float bni = bih[2000 + gn];
        float bnh = bhh[2000 + gn];
#pragma unroll
        for (int i = 0; i < 2; i++)
#pragma unroll
            for (int r = 0; r < 4; r++) {
                int gm = m0 + wr * 32 + i * 16 + r4 + r;
                if (gm >= N_NODES) continue;
                float rg = sigmoidf_(aR[i][j][r] + br);
                float zg = sigmoidf_(aZ[i][j][r] + bz);
                float ng = tanhf(aN[i][j][r] + bni + rg * (aH[i][j][r] + bnh));
                size_t idx = (size_t)gm * KP + gn;
                float hp = b2f(h[idx]);
                hout[idx] = f2b((1.0f - zg) * ng + zg * hp);
            }
    }
}

// ---------------------------------------------------------------------------
// out[row] (fp32) = relu(h[row]) . fc_w + fc_b — one wave per row
// ---------------------------------------------------------------------------
__global__ __launch_bounds__(256) void fc_out(const u16* __restrict__ h,
                                              const float* __restrict__ fw,
                                              const float* __restrict__ fb,
                                              float* __restrict__ out) {
    int row = blockIdx.x * 4 + (threadIdx.x >> 6);
    int lane = threadIdx.x & 63;
    if (row >= N_NODES) return;
    float s = 0.0f;
    for (int i = 0; i < 4; i++) {
        int c = lane + 64 * i;
        if (c < 250) {
            uint2 v = *(const uint2*)(h + (size_t)row * KP + c * 4);
            float4 w = *(const float4*)(fw + c * 4);
            const u16* pv = (const u16*)&v;
            float h0 = b2f(pv[0]), h1 = b2f(pv[1]), h2 = b2f(pv[2]), h3 = b2f(pv[3]);
            s += (h0 > 0.0f ? h0 : 0.0f) * w.x;
            s += (h1 > 0.0f ? h1 : 0.0f) * w.y;
            s += (h2 > 0.0f ? h2 : 0.0f) * w.z;
            s += (h3 > 0.0f ? h3 : 0.0f) * w.w;
        }
    }
    for (int off = 32; off > 0; off >>= 1) s += __shfl_down(s, off, 64);
    if (lane == 0) out[row] = s + fb[0];
}

// ---------------------------------------------------------------------------
extern "C" void kernel_launch(void* const* d_in, const int* in_sizes, int n_in,
                              void* d_out, int out_size, void* d_ws, size_t ws_size,
                              hipStream_t stream) {
    const float* x   = (const float*)d_in[0];
    const int*   ei  = (const int*)d_in[1];
    const float* ew  = (const float*)d_in[2];
    const float* W   = (const float*)d_in[3];
    const float* wih = (const float*)d_in[4];
    const float* whh = (const float*)d_in[5];
    const float* bih = (const float*)d_in[6];
    const float* bhh = (const float*)d_in[7];
    const float* fw  = (const float*)d_in[8];
    const float* fb  = (const float*)d_in[9];
    float* out = (float*)d_out;

    // workspace (~144 MB); SP gives each node buffer 20096-row slack
    char* ws = (char*)d_ws;
    u16* xb   = (u16*)(ws);                    // [20000+][1024] bf16
    u16* bufA = (u16*)(ws + (size_t)SP);
    u16* bufB = (u16*)(ws + (size_t)2 * SP);   // agg
    u16* Wt   = (u16*)(ws + 123600000);        // 6.3 MB [3][1024][1024]
    u16* wcat = (u16*)(ws + 130000000);        // 12.6 MB [3][1024][2048]
    int* cnt  = (int*)(ws + 143000000);        // 80 KB
    int* cur  = (int*)(ws + 143100000);        // 80 KB
    int* ofs  = (int*)(ws + 143200000);        // 80 KB + 4
    int* bkt  = (int*)(ws + 143300096);        // 640 KB

    // one-time conversions + CSR build
    cvt_rows<<<N_NODES, 256, 0, stream>>>(x, xb);
    cvt_wcat<<<3000, 256, 0, stream>>>(wih, whh, wcat);
    transpose_w<<<dim3(32, 32, 3), dim3(32, 8), 0, stream>>>(W, Wt);
    hipMemsetAsync(cnt, 0, 80000, stream);
    hipMemsetAsync(cur, 0, 80000, stream);
    count_edges<<<625, 256, 0, stream>>>(ei, cnt);
    scan_offsets<<<1, 1024, 0, stream>>>(cnt, ofs);
    fill_buckets<<<625, 256, 0, stream>>>(ei, ofs, cur, bkt);

    // layer 0: h = xb; m -> bufA; agg -> bufB; h1 -> bufA (m dead)
    gemm_bt<<<1256, 256, 0, stream>>>(xb, Wt, bufA);
    node_agg<<<N_NODES, 256, 0, stream>>>(ei, ew, ofs, bkt, bufA, bufB);
    gru_fused<<<5008, 256, 0, stream>>>(bufB, xb, wcat, bih, bhh, bufA);

    // layer 1: h = bufA; m -> xb; agg -> bufB; h2 -> xb
    gemm_bt<<<1256, 256, 0, stream>>>(bufA, Wt + 1048576, xb);
    node_agg<<<N_NODES, 256, 0, stream>>>(ei, ew, ofs, bkt, xb, bufB);
    gru_fused<<<5008, 256, 0, stream>>>(bufB, bufA, wcat, bih, bhh, xb);

    // layer 2: h = xb; m -> bufA; agg -> bufB; h3 -> bufA
    gemm_bt<<<1256, 256, 0, stream>>>(xb, Wt + 2097152, bufA);
    node_agg<<<N_NODES, 256, 0, stream>>>(ei, ew, ofs, bkt, bufA, bufB);
    gru_fused<<<5008, 256, 0, stream>>>(bufB, xb, wcat, bih, bhh, bufA);

    // out = relu(h3) @ fc_w^T + fc_b
    fc_out<<<5000, 256, 0, stream>>>(bufA, fw, fb, out);
}

// Round 7
// 1719.666 us; speedup vs baseline: 1.0867x; 1.0867x over previous
//
#include <hip/hip_runtime.h>

typedef unsigned short u16;
typedef unsigned int u32;
typedef __attribute__((ext_vector_type(8))) short bf16x8;
typedef __attribute__((ext_vector_type(4))) float f32x4;

#define N_NODES 20000
#define N_EDGES 160000
#define DDIM    1000
#define KP      1024            // padded K / row stride (elements)
#define SP      41200000        // node-buffer spacing (bytes)

__device__ __forceinline__ float b2f(u16 u) {
    union { u32 i; float f; } v; v.i = ((u32)u) << 16; return v.f;
}
__device__ __forceinline__ u16 f2b(float f) {
    union { float f; u32 i; } v; v.f = f;
    u32 r = v.i + 0x7FFFu + ((v.i >> 16) & 1u);
    return (u16)(r >> 16);
}
__device__ __forceinline__ u32 pack2(float a, float b) {
    return (u32)f2b(a) | ((u32)f2b(b) << 16);
}
__device__ __forceinline__ f32x4 mfma16(bf16x8 a, bf16x8 b, f32x4 c) {
    return __builtin_amdgcn_mfma_f32_16x16x32_bf16(a, b, c, 0, 0, 0);
}
__device__ __forceinline__ float sigmoidf_(float x) { return 1.0f / (1.0f + expf(-x)); }

// async global->LDS DMA, 16 B per lane; lds dest = wave-uniform base + lane*16
__device__ __forceinline__ void gl2lds16(const u16* g, u16* l) {
    __builtin_amdgcn_global_load_lds(
        (const __attribute__((address_space(1))) u32*)g,
        (__attribute__((address_space(3))) u32*)l, 16, 0, 0);
}

// ---------------------------------------------------------------------------
// fp32 [rows][1000] -> bf16 [rows][1024], zero-padded cols. One block per row.
// ---------------------------------------------------------------------------
__global__ __launch_bounds__(256) void cvt_rows(const float* __restrict__ in,
                                                u16* __restrict__ out) {
    int r = blockIdx.x, c = threadIdx.x * 4;
    u32 o[2] = {0, 0};
    if (c < DDIM) {
        float4 v = *(const float4*)(in + (size_t)r * DDIM + c);
        o[0] = pack2(v.x, v.y); o[1] = pack2(v.z, v.w);
    }
    *(uint2*)(out + (size_t)r * KP + c) = *(const uint2*)o;
}

// ---------------------------------------------------------------------------
// Stacked GRU weights: wcat[g][n][0:1024) = wih[g*1000+n][:], zero-pad;
//                      wcat[g][n][1024:2048) = whh[g*1000+n][:], zero-pad.
// ---------------------------------------------------------------------------
__global__ __launch_bounds__(256) void cvt_wcat(const float* __restrict__ wih,
                                                const float* __restrict__ whh,
                                                u16* __restrict__ wcat) {
    int r = blockIdx.x;                  // 0..2999
    int g = r / 1000, n = r - g * 1000;
    int c = threadIdx.x * 4;             // 0..1020
    u16* dst = wcat + ((size_t)g * 1024 + n) * 2048;
    u32 o[2] = {0, 0};
    if (c < DDIM) {
        float4 v = *(const float4*)(wih + (size_t)r * DDIM + c);
        o[0] = pack2(v.x, v.y); o[1] = pack2(v.z, v.w);
    }
    *(uint2*)(dst + c) = *(const uint2*)o;
    o[0] = 0; o[1] = 0;
    if (c < DDIM) {
        float4 v = *(const float4*)(whh + (size_t)r * DDIM + c);
        o[0] = pack2(v.x, v.y); o[1] = pack2(v.z, v.w);
    }
    *(uint2*)(dst + 1024 + c) = *(const uint2*)o;
}

// ---------------------------------------------------------------------------
// weight[l] fp32 [k<1000][n<1000] -> Wt bf16 [n<1024][k<1024], zero-padded.
// ---------------------------------------------------------------------------
__global__ __launch_bounds__(256) void transpose_w(const float* __restrict__ W,
                                                   u16* __restrict__ Wt) {
    __shared__ u16 t[32][33];
    int l = blockIdx.z;
    int nb = blockIdx.x * 32, kb = blockIdx.y * 32;
    int x = threadIdx.x, y = threadIdx.y;   // block (32, 8)
    const float* Wl = W + (size_t)l * 1000000;
    u16* Wtl = Wt + (size_t)l * (KP * KP);
    for (int i = 0; i < 32; i += 8) {
        int k = kb + y + i, n = nb + x;
        t[y + i][x] = (k < DDIM && n < DDIM) ? f2b(Wl[(size_t)k * DDIM + n]) : (u16)0;
    }
    __syncthreads();
    for (int i = 0; i < 32; i += 8) {
        int n = nb + y + i, k = kb + x;
        Wtl[(size_t)n * KP + k] = t[x][y + i];
    }
}

// ---------------------------------------------------------------------------
// CSR build (edge list constant): count -> scan -> fill
// ---------------------------------------------------------------------------
__global__ __launch_bounds__(256) void count_edges(const int* __restrict__ ei,
                                                   int* __restrict__ cnt) {
    int e = blockIdx.x * 256 + threadIdx.x;
    if (e < N_EDGES) atomicAdd(&cnt[ei[N_EDGES + e]], 1);
}

__global__ __launch_bounds__(1024) void scan_offsets(const int* __restrict__ cnt,
                                                     int* __restrict__ ofs) {
    __shared__ int s[1024];
    const int CH = 20;
    int t = threadIdx.x;
    int base = t * CH;
    int loc[CH];
    int sum = 0;
    for (int j = 0; j < CH; j++) {
        int i = base + j;
        loc[j] = sum;
        sum += (i < N_NODES) ? cnt[i] : 0;
    }
    s[t] = sum;
    __syncthreads();
    for (int d = 1; d < 1024; d <<= 1) {
        int v = (t >= d) ? s[t - d] : 0;
        __syncthreads();
        s[t] += v;
        __syncthreads();
    }
    int excl = s[t] - sum;
    for (int j = 0; j < CH; j++) {
        int i = base + j;
        if (i < N_NODES) ofs[i] = excl + loc[j];
    }
    if (t == 0) ofs[N_NODES] = N_EDGES;
}

__global__ __launch_bounds__(256) void fill_buckets(const int* __restrict__ ei,
                                                    const int* __restrict__ ofs,
                                                    int* __restrict__ cur,
                                                    int* __restrict__ bkt) {
    int e = blockIdx.x * 256 + threadIdx.x;
    if (e >= N_EDGES) return;
    int d = ei[N_EDGES + e];
    int pos = atomicAdd(&cur[d], 1);
    bkt[ofs[d] + pos] = e;
}

// ---------------------------------------------------------------------------
// agg[node] = sum_{e: dst=node} m[src(e)] * ew[e] — one block/node, no atomics
// ---------------------------------------------------------------------------
__global__ __launch_bounds__(256) void node_agg(const int* __restrict__ ei,
                                                const float* __restrict__ ew,
                                                const int* __restrict__ ofs,
                                                const int* __restrict__ bkt,
                                                const u16* __restrict__ m,
                                                u16* __restrict__ agg) {
    __shared__ int   s_src[64];
    __shared__ float s_w[64];
    int node = blockIdx.x;
    int t = threadIdx.x;                 // t<250 owns features [4t, 4t+4)
    int beg = ofs[node], end = ofs[node + 1];
    float4 acc = {0.f, 0.f, 0.f, 0.f};
    for (int cb = beg; cb < end; cb += 64) {
        int n = min(64, end - cb);
        if (t < n) {
            int e = bkt[cb + t];
            s_src[t] = ei[e];
            s_w[t]   = ew[e];
        }
        __syncthreads();
        if (t < 250) {
            for (int j = 0; j < n; j++) {
                int src = s_src[j];
                float w = s_w[j];
                uint2 v = *(const uint2*)(m + (size_t)src * KP + t * 4);
                const u16* p = (const u16*)&v;
                acc.x += b2f(p[0]) * w;
                acc.y += b2f(p[1]) * w;
                acc.z += b2f(p[2]) * w;
                acc.w += b2f(p[3]) * w;
            }
        }
        __syncthreads();
    }
    if (t < 250) {
        u32 o[2] = {pack2(acc.x, acc.y), pack2(acc.z, acc.w)};
        *(uint2*)(agg + (size_t)node * KP + t * 4) = *(const uint2*)o;
    }
}

// ---------------------------------------------------------------------------
// C[m<20000][n<1000] = A[m][k<1024] @ Bt[n][k<1024]^T  (bf16, fp32 acc)
// 128x128 tile, BK=64, XOR-swizzled staging (conflict-free ds_read_b128).
// ---------------------------------------------------------------------------
__global__ __launch_bounds__(256) void gemm_bt(const u16* __restrict__ A,
                                               const u16* __restrict__ Bt,
                                               u16* __restrict__ C) {
    __shared__ u16 S[16384];             // Sa [128][64] @0, Sb @8192 (u16 idx)
    int tid = threadIdx.x;
    int lane = tid & 63, wave = tid >> 6;
    int wr = wave >> 1, wc = wave & 1;
    int bid = blockIdx.x;
    int m0 = (bid >> 3) * 128, n0 = (bid & 7) * 128;

    // staging map: LDS slot c (row=c>>3, s=c&7) <- global chunk kc = s^(row&7)
    int aoff[4], boff[4];
#pragma unroll
    for (int i = 0; i < 4; i++) {
        int c = tid + 256 * i;
        int row = c >> 3, sl = c & 7;
        int kc = sl ^ (row & 7);
        aoff[i] = (m0 + row) * KP + kc * 8;
        boff[i] = (n0 + row) * KP + kc * 8;
    }
    f32x4 acc[4][4] = {};
    int fr = lane & 15, q = lane >> 4, sw = fr & 7;

    for (int k0 = 0; k0 < KP; k0 += 64) {
#pragma unroll
        for (int i = 0; i < 4; i++) {
            gl2lds16(A + aoff[i] + k0, &S[tid * 8 + 2048 * i]);
            gl2lds16(Bt + boff[i] + k0, &S[8192 + tid * 8 + 2048 * i]);
        }
        __syncthreads();
#pragma unroll
        for (int ks = 0; ks < 2; ks++) {
            int kx = ((ks * 4 + q) ^ sw) * 8;
            bf16x8 af[4], bf[4];
#pragma unroll
            for (int i = 0; i < 4; i++)
                af[i] = *(const bf16x8*)&S[(wr * 64 + i * 16 + fr) * 64 + kx];
#pragma unroll
            for (int j = 0; j < 4; j++)
                bf[j] = *(const bf16x8*)&S[8192 + (wc * 64 + j * 16 + fr) * 64 + kx];
#pragma unroll
            for (int i = 0; i < 4; i++)
#pragma unroll
                for (int j = 0; j < 4; j++)
                    acc[i][j] = mfma16(af[i], bf[j], acc[i][j]);
        }
        __syncthreads();
    }

    int cc = lane & 15, r4 = q * 4;
#pragma unroll
    for (int i = 0; i < 4; i++)
#pragma unroll
        for (int j = 0; j < 4; j++) {
            int gn = n0 + wc * 64 + j * 16 + cc;
            if (gn >= DDIM) continue;
#pragma unroll
            for (int r = 0; r < 4; r++) {
                int gm = m0 + wr * 64 + i * 16 + r4 + r;
                if (gm < N_NODES) C[(size_t)gm * KP + gn] = f2b(acc[i][j][r]);
            }
        }
}

// ---------------------------------------------------------------------------
// Fused GRU, stacked-K: r,z over K=2048=[agg|h]; i_n first half, h_n second.
// Tile 64 rows x 64 gate-cols, BK=64, XOR-swizzled staging, LDS 32 KB.
// wcat = [3][1024][2048]; slabs r,z,n; cols 0:1024 = w_ih, 1024:2048 = w_hh.
// ---------------------------------------------------------------------------
__global__ __launch_bounds__(256) void gru_fused(const u16* __restrict__ agg,
                                                 const u16* __restrict__ h,
                                                 const u16* __restrict__ wcat,
                                                 const float* __restrict__ bih,
                                                 const float* __restrict__ bhh,
                                                 u16* __restrict__ hout) {
    __shared__ u16 S[16384];   // A @0, W0 @4096, W1 @8192, W2 @12288 (u16 idx)
    int tid = threadIdx.x;
    int lane = tid & 63, wave = tid >> 6;
    int wr = wave >> 1, wc = wave & 1;

    int bid = blockIdx.x;                 // grid 5008 = 8 xcd x 626
    int xcd = bid & 7;
    int s = bid >> 3;                     // 0..625
    int hi = (s >= 313) ? 1 : 0;
    int m0 = (s - hi * 313) * 64;
    int n0 = (xcd * 2 + hi) * 64;

    // staging map (per slab, 512 chunks): slot c (row=c>>3, s=c&7), kc=s^(row&7)
    int aoff[2], woff[2];
#pragma unroll
    for (int i = 0; i < 2; i++) {
        int c = tid + 256 * i;
        int row = c >> 3, sl = c & 7;
        int kc = sl ^ (row & 7);
        aoff[i] = (m0 + row) * KP + kc * 8;
        woff[i] = (n0 + row) * 2048 + kc * 8;
    }
    f32x4 aR[2][2] = {}, aZ[2][2] = {}, aN[2][2] = {}, aH[2][2] = {};
    int fr = lane & 15, q = lane >> 4, sw = fr & 7;

#define GRU_PHASE(APTR, K0W, AN)                                              \
    for (int kk = 0; kk < 16; kk++) {                                         \
        int ka = kk * 64, kw = K0W + kk * 64;                                 \
        _Pragma("unroll")                                                     \
        for (int i = 0; i < 2; i++) {                                         \
            gl2lds16(APTR + aoff[i] + ka, &S[tid * 8 + 2048 * i]);            \
            gl2lds16(wcat + woff[i] + kw, &S[4096 + tid * 8 + 2048 * i]);     \
            gl2lds16(wcat + 2097152 + woff[i] + kw,                           \
                     &S[8192 + tid * 8 + 2048 * i]);                          \
            gl2lds16(wcat + 4194304 + woff[i] + kw,                           \
                     &S[12288 + tid * 8 + 2048 * i]);                         \
        }                                                                     \
        __syncthreads();                                                      \
        _Pragma("unroll")                                                     \
        for (int ks = 0; ks < 2; ks++) {                                      \
            int kx = ((ks * 4 + q) ^ sw) * 8;                                 \
            bf16x8 aa[2], w0[2], w1[2], w2[2];                                \
            _Pragma("unroll")                                                 \
            for (int i = 0; i < 2; i++) {                                     \
                int ra = (wr * 32 + i * 16 + fr) * 64 + kx;                   \
                int rb = (wc * 32 + i * 16 + fr) * 64 + kx;                   \
                aa[i] = *(const bf16x8*)&S[ra];                               \
                w0[i] = *(const bf16x8*)&S[4096 + rb];                        \
                w1[i] = *(const bf16x8*)&S[8192 + rb];                        \
                w2[i] = *(const bf16x8*)&S[12288 + rb];                       \
            }                                                                 \
            _Pragma("unroll")                                                 \
            for (int i = 0; i < 2; i++)                                       \
                _Pragma("unroll")                                             \
                for (int j = 0; j < 2; j++) {                                 \
                    aR[i][j] = mfma16(aa[i], w0[j], aR[i][j]);                \
                    aZ[i][j] = mfma16(aa[i], w1[j], aZ[i][j]);                \
                    AN[i][j] = mfma16(aa[i], w2[j], AN[i][j]);                \
                }                                                             \
        }                                                                     \
        __syncthreads();                                                      \
    }

    GRU_PHASE(agg, 0, aN)      // k 0..1023:    agg vs w_ih -> r, z, i_n
    GRU_PHASE(h, 1024, aH)     // k 1024..2047: h   vs w_hh -> r, z, h_n
#undef GRU_PHASE

    int cc = lane & 15, r4 = q * 4;
#pragma unroll
    for (int j = 0; j < 2; j++) {
        int gn = n0 + wc * 32 + j * 16 + cc;
        if (gn >= DDIM) continue;
        float br  = bih[gn] + bhh[gn];
        float bz  = bih[1000 + gn] + bhh[1000 + gn];
        float bni = bih[2000 + gn];
        float bnh = bhh[2000 + gn];
#pragma unroll
        for (int i = 0; i < 2; i++)
#pragma unroll
            for (int r = 0; r < 4; r++) {
                int gm = m0 + wr * 32 + i * 16 + r4 + r;
                if (gm >= N_NODES) continue;
                float rg = sigmoidf_(aR[i][j][r] + br);
                float zg = sigmoidf_(aZ[i][j][r] + bz);
                float ng = tanhf(aN[i][j][r] + bni + rg * (aH[i][j][r] + bnh));
                size_t idx = (size_t)gm * KP + gn;
                float hp = b2f(h[idx]);
                hout[idx] = f2b((1.0f - zg) * ng + zg * hp);
            }
    }
}

// ---------------------------------------------------------------------------
// out[row] (fp32) = relu(h[row]) . fc_w + fc_b — one wave per row
// ---------------------------------------------------------------------------
__global__ __launch_bounds__(256) void fc_out(const u16* __restrict__ h,
                                              const float* __restrict__ fw,
                                              const float* __restrict__ fb,
                                              float* __restrict__ out) {
    int row = blockIdx.x * 4 + (threadIdx.x >> 6);
    int lane = threadIdx.x & 63;
    if (row >= N_NODES) return;
    float s = 0.0f;
    for (int i = 0; i < 4; i++) {
        int c = lane + 64 * i;
        if (c < 250) {
            uint2 v = *(const uint2*)(h + (size_t)row * KP + c * 4);
            float4 w = *(const float4*)(fw + c * 4);
            const u16* pv = (const u16*)&v;
            float h0 = b2f(pv[0]), h1 = b2f(pv[1]), h2 = b2f(pv[2]), h3 = b2f(pv[3]);
            s += (h0 > 0.0f ? h0 : 0.0f) * w.x;
            s += (h1 > 0.0f ? h1 : 0.0f) * w.y;
            s += (h2 > 0.0f ? h2 : 0.0f) * w.z;
            s += (h3 > 0.0f ? h3 : 0.0f) * w.w;
        }
    }
    for (int off = 32; off > 0; off >>= 1) s += __shfl_down(s, off, 64);
    if (lane == 0) out[row] = s + fb[0];
}

// ---------------------------------------------------------------------------
extern "C" void kernel_launch(void* const* d_in, const int* in_sizes, int n_in,
                              void* d_out, int out_size, void* d_ws, size_t ws_size,
                              hipStream_t stream) {
    const float* x   = (const float*)d_in[0];
    const int*   ei  = (const int*)d_in[1];
    const float* ew  = (const float*)d_in[2];
    const float* W   = (const float*)d_in[3];
    const float* wih = (const float*)d_in[4];
    const float* whh = (const float*)d_in[5];
    const float* bih = (const float*)d_in[6];
    const float* bhh = (const float*)d_in[7];
    const float* fw  = (const float*)d_in[8];
    const float* fb  = (const float*)d_in[9];
    float* out = (float*)d_out;

    // workspace (~144 MB)
    char* ws = (char*)d_ws;
    u16* xb   = (u16*)(ws);                    // [20000+][1024] bf16
    u16* bufA = (u16*)(ws + (size_t)SP);
    u16* bufB = (u16*)(ws + (size_t)2 * SP);   // agg
    u16* Wt   = (u16*)(ws + 123600000);        // 6.3 MB [3][1024][1024]
    u16* wcat = (u16*)(ws + 130000000);        // 12.6 MB [3][1024][2048]
    int* cnt  = (int*)(ws + 143000000);        // 80 KB
    int* cur  = (int*)(ws + 143100000);        // 80 KB
    int* ofs  = (int*)(ws + 143200000);        // 80 KB + 4
    int* bkt  = (int*)(ws + 143300096);        // 640 KB

    // one-time conversions + CSR build
    cvt_rows<<<N_NODES, 256, 0, stream>>>(x, xb);
    cvt_wcat<<<3000, 256, 0, stream>>>(wih, whh, wcat);
    transpose_w<<<dim3(32, 32, 3), dim3(32, 8), 0, stream>>>(W, Wt);
    hipMemsetAsync(cnt, 0, 80000, stream);
    hipMemsetAsync(cur, 0, 80000, stream);
    count_edges<<<625, 256, 0, stream>>>(ei, cnt);
    scan_offsets<<<1, 1024, 0, stream>>>(cnt, ofs);
    fill_buckets<<<625, 256, 0, stream>>>(ei, ofs, cur, bkt);

    // layer 0: h = xb; m -> bufA; agg -> bufB; h1 -> bufA (m dead)
    gemm_bt<<<1256, 256, 0, stream>>>(xb, Wt, bufA);
    node_agg<<<N_NODES, 256, 0, stream>>>(ei, ew, ofs, bkt, bufA, bufB);
    gru_fused<<<5008, 256, 0, stream>>>(bufB, xb, wcat, bih, bhh, bufA);

    // layer 1: h = bufA; m -> xb; agg -> bufB; h2 -> xb
    gemm_bt<<<1256, 256, 0, stream>>>(bufA, Wt + 1048576, xb);
    node_agg<<<N_NODES, 256, 0, stream>>>(ei, ew, ofs, bkt, xb, bufB);
    gru_fused<<<5008, 256, 0, stream>>>(bufB, bufA, wcat, bih, bhh, xb);

    // layer 2: h = xb; m -> bufA; agg -> bufB; h3 -> bufA
    gemm_bt<<<1256, 256, 0, stream>>>(xb, Wt + 2097152, bufA);
    node_agg<<<N_NODES, 256, 0, stream>>>(ei, ew, ofs, bkt, bufA, bufB);
    gru_fused<<<5008, 256, 0, stream>>>(bufB, xb, wcat, bih, bhh, bufA);

    // out = relu(h3) @ fc_w^T + fc_b
    fc_out<<<5000, 256, 0, stream>>>(bufA, fw, fb, out);
}

// Round 8
// 1509.113 us; speedup vs baseline: 1.2384x; 1.1395x over previous
//
#include <hip/hip_runtime.h>

typedef unsigned short u16;
typedef unsigned int u32;
typedef __attribute__((ext_vector_type(8))) short bf16x8;
typedef __attribute__((ext_vector_type(4))) float f32x4;

#define N_NODES 20000
#define N_EDGES 160000
#define DDIM    1000
#define KP      1024            // padded K / row stride (elements)
#define SP      41200000        // node-buffer spacing (bytes)

__device__ __forceinline__ float b2f(u16 u) {
    union { u32 i; float f; } v; v.i = ((u32)u) << 16; return v.f;
}
__device__ __forceinline__ u16 f2b(float f) {
    union { float f; u32 i; } v; v.f = f;
    u32 r = v.i + 0x7FFFu + ((v.i >> 16) & 1u);
    return (u16)(r >> 16);
}
__device__ __forceinline__ u32 pack2(float a, float b) {
    return (u32)f2b(a) | ((u32)f2b(b) << 16);
}
__device__ __forceinline__ f32x4 mfma16(bf16x8 a, bf16x8 b, f32x4 c) {
    return __builtin_amdgcn_mfma_f32_16x16x32_bf16(a, b, c, 0, 0, 0);
}
__device__ __forceinline__ float sigmoidf_(float x) { return 1.0f / (1.0f + expf(-x)); }

// async global->LDS DMA, 16 B per lane; lds dest = wave-uniform base + lane*16
__device__ __forceinline__ void gl2lds16(const u16* g, u16* l) {
    __builtin_amdgcn_global_load_lds(
        (const __attribute__((address_space(1))) u32*)g,
        (__attribute__((address_space(3))) u32*)l, 16, 0, 0);
}

// ---------------------------------------------------------------------------
// fp32 [rows][1000] -> bf16 [rows][1024], zero-padded cols. One block per row.
// ---------------------------------------------------------------------------
__global__ __launch_bounds__(256) void cvt_rows(const float* __restrict__ in,
                                                u16* __restrict__ out) {
    int r = blockIdx.x, c = threadIdx.x * 4;
    u32 o[2] = {0, 0};
    if (c < DDIM) {
        float4 v = *(const float4*)(in + (size_t)r * DDIM + c);
        o[0] = pack2(v.x, v.y); o[1] = pack2(v.z, v.w);
    }
    *(uint2*)(out + (size_t)r * KP + c) = *(const uint2*)o;
}

// ---------------------------------------------------------------------------
// Stacked GRU weights: wcat[g][n][0:1024) = wih[g*1000+n][:], zero-pad;
//                      wcat[g][n][1024:2048) = whh[g*1000+n][:], zero-pad.
// ---------------------------------------------------------------------------
__global__ __launch_bounds__(256) void cvt_wcat(const float* __restrict__ wih,
                                                const float* __restrict__ whh,
                                                u16* __restrict__ wcat) {
    int r = blockIdx.x;                  // 0..2999
    int g = r / 1000, n = r - g * 1000;
    int c = threadIdx.x * 4;             // 0..1020
    u16* dst = wcat + ((size_t)g * 1024 + n) * 2048;
    u32 o[2] = {0, 0};
    if (c < DDIM) {
        float4 v = *(const float4*)(wih + (size_t)r * DDIM + c);
        o[0] = pack2(v.x, v.y); o[1] = pack2(v.z, v.w);
    }
    *(uint2*)(dst + c) = *(const uint2*)o;
    o[0] = 0; o[1] = 0;
    if (c < DDIM) {
        float4 v = *(const float4*)(whh + (size_t)r * DDIM + c);
        o[0] = pack2(v.x, v.y); o[1] = pack2(v.z, v.w);
    }
    *(uint2*)(dst + 1024 + c) = *(const uint2*)o;
}

// ---------------------------------------------------------------------------
// weight[l] fp32 [k<1000][n<1000] -> Wt bf16 [n<1024][k<1024], zero-padded.
// ---------------------------------------------------------------------------
__global__ __launch_bounds__(256) void transpose_w(const float* __restrict__ W,
                                                   u16* __restrict__ Wt) {
    __shared__ u16 t[32][33];
    int l = blockIdx.z;
    int nb = blockIdx.x * 32, kb = blockIdx.y * 32;
    int x = threadIdx.x, y = threadIdx.y;   // block (32, 8)
    const float* Wl = W + (size_t)l * 1000000;
    u16* Wtl = Wt + (size_t)l * (KP * KP);
    for (int i = 0; i < 32; i += 8) {
        int k = kb + y + i, n = nb + x;
        t[y + i][x] = (k < DDIM && n < DDIM) ? f2b(Wl[(size_t)k * DDIM + n]) : (u16)0;
    }
    __syncthreads();
    for (int i = 0; i < 32; i += 8) {
        int n = nb + y + i, k = kb + x;
        Wtl[(size_t)n * KP + k] = t[x][y + i];
    }
}

// ---------------------------------------------------------------------------
// CSR build (edge list constant): count -> scan -> fill
// ---------------------------------------------------------------------------
__global__ __launch_bounds__(256) void count_edges(const int* __restrict__ ei,
                                                   int* __restrict__ cnt) {
    int e = blockIdx.x * 256 + threadIdx.x;
    if (e < N_EDGES) atomicAdd(&cnt[ei[N_EDGES + e]], 1);
}

__global__ __launch_bounds__(1024) void scan_offsets(const int* __restrict__ cnt,
                                                     int* __restrict__ ofs) {
    __shared__ int s[1024];
    const int CH = 20;
    int t = threadIdx.x;
    int base = t * CH;
    int loc[CH];
    int sum = 0;
    for (int j = 0; j < CH; j++) {
        int i = base + j;
        loc[j] = sum;
        sum += (i < N_NODES) ? cnt[i] : 0;
    }
    s[t] = sum;
    __syncthreads();
    for (int d = 1; d < 1024; d <<= 1) {
        int v = (t >= d) ? s[t - d] : 0;
        __syncthreads();
        s[t] += v;
        __syncthreads();
    }
    int excl = s[t] - sum;
    for (int j = 0; j < CH; j++) {
        int i = base + j;
        if (i < N_NODES) ofs[i] = excl + loc[j];
    }
    if (t == 0) ofs[N_NODES] = N_EDGES;
}

__global__ __launch_bounds__(256) void fill_buckets(const int* __restrict__ ei,
                                                    const int* __restrict__ ofs,
                                                    int* __restrict__ cur,
                                                    int* __restrict__ bkt) {
    int e = blockIdx.x * 256 + threadIdx.x;
    if (e >= N_EDGES) return;
    int d = ei[N_EDGES + e];
    int pos = atomicAdd(&cur[d], 1);
    bkt[ofs[d] + pos] = e;
}

// ---------------------------------------------------------------------------
// agg[node] = sum_{e: dst=node} m[src(e)] * ew[e] — one block/node, no atomics
// ---------------------------------------------------------------------------
__global__ __launch_bounds__(256) void node_agg(const int* __restrict__ ei,
                                                const float* __restrict__ ew,
                                                const int* __restrict__ ofs,
                                                const int* __restrict__ bkt,
                                                const u16* __restrict__ m,
                                                u16* __restrict__ agg) {
    __shared__ int   s_src[64];
    __shared__ float s_w[64];
    int node = blockIdx.x;
    int t = threadIdx.x;                 // t<250 owns features [4t, 4t+4)
    int beg = ofs[node], end = ofs[node + 1];
    float4 acc = {0.f, 0.f, 0.f, 0.f};
    for (int cb = beg; cb < end; cb += 64) {
        int n = min(64, end - cb);
        if (t < n) {
            int e = bkt[cb + t];
            s_src[t] = ei[e];
            s_w[t]   = ew[e];
        }
        __syncthreads();
        if (t < 250) {
            for (int j = 0; j < n; j++) {
                int src = s_src[j];
                float w = s_w[j];
                uint2 v = *(const uint2*)(m + (size_t)src * KP + t * 4);
                const u16* p = (const u16*)&v;
                acc.x += b2f(p[0]) * w;
                acc.y += b2f(p[1]) * w;
                acc.z += b2f(p[2]) * w;
                acc.w += b2f(p[3]) * w;
            }
        }
        __syncthreads();
    }
    if (t < 250) {
        u32 o[2] = {pack2(acc.x, acc.y), pack2(acc.z, acc.w)};
        *(uint2*)(agg + (size_t)node * KP + t * 4) = *(const uint2*)o;
    }
}

// ---------------------------------------------------------------------------
// C[m<20000][n<1000] = A[m][k<1024] @ Bt[n][k<1024]^T  (bf16, fp32 acc)
// 128x128 tile, BK=64, XOR-swizzled staging (conflict-free ds_read_b128).
// ---------------------------------------------------------------------------
__global__ __launch_bounds__(256) void gemm_bt(const u16* __restrict__ A,
                                               const u16* __restrict__ Bt,
                                               u16* __restrict__ C) {
    __shared__ u16 S[16384];             // Sa [128][64] @0, Sb @8192 (u16 idx)
    int tid = threadIdx.x;
    int lane = tid & 63, wave = tid >> 6;
    int wr = wave >> 1, wc = wave & 1;
    int bid = blockIdx.x;
    int m0 = (bid >> 3) * 128, n0 = (bid & 7) * 128;

    // staging map: LDS slot c (row=c>>3, s=c&7) <- global chunk kc = s^(row&7)
    int aoff[4], boff[4];
#pragma unroll
    for (int i = 0; i < 4; i++) {
        int c = tid + 256 * i;
        int row = c >> 3, sl = c & 7;
        int kc = sl ^ (row & 7);
        aoff[i] = (m0 + row) * KP + kc * 8;
        boff[i] = (n0 + row) * KP + kc * 8;
    }
    f32x4 acc[4][4] = {};
    int fr = lane & 15, q = lane >> 4, sw = fr & 7;

    for (int k0 = 0; k0 < KP; k0 += 64) {
#pragma unroll
        for (int i = 0; i < 4; i++) {
            gl2lds16(A + aoff[i] + k0, &S[tid * 8 + 2048 * i]);
            gl2lds16(Bt + boff[i] + k0, &S[8192 + tid * 8 + 2048 * i]);
        }
        __syncthreads();
#pragma unroll
        for (int ks = 0; ks < 2; ks++) {
            int kx = ((ks * 4 + q) ^ sw) * 8;
            bf16x8 af[4], bf[4];
#pragma unroll
            for (int i = 0; i < 4; i++)
                af[i] = *(const bf16x8*)&S[(wr * 64 + i * 16 + fr) * 64 + kx];
#pragma unroll
            for (int j = 0; j < 4; j++)
                bf[j] = *(const bf16x8*)&S[8192 + (wc * 64 + j * 16 + fr) * 64 + kx];
#pragma unroll
            for (int i = 0; i < 4; i++)
#pragma unroll
                for (int j = 0; j < 4; j++)
                    acc[i][j] = mfma16(af[i], bf[j], acc[i][j]);
        }
        __syncthreads();
    }

    int cc = lane & 15, r4 = q * 4;
#pragma unroll
    for (int i = 0; i < 4; i++)
#pragma unroll
        for (int j = 0; j < 4; j++) {
            int gn = n0 + wc * 64 + j * 16 + cc;
            if (gn >= DDIM) continue;
#pragma unroll
            for (int r = 0; r < 4; r++) {
                int gm = m0 + wr * 64 + i * 16 + r4 + r;
                if (gm < N_NODES) C[(size_t)gm * KP + gn] = f2b(acc[i][j][r]);
            }
        }
}

// ---------------------------------------------------------------------------
// Fused GRU, stacked-K: r,z over K=2048=[agg|h]; i_n first half, h_n second.
// Tile 128 rows x 64 gate-cols, BK=64, XOR-swizzled staging, LDS 40 KB.
// wcat = [3][1024][2048]; slabs r,z,n; cols 0:1024 = w_ih, 1024:2048 = w_hh.
// Per step: 10 DMA issues/thread, 48 MFMA/wave. acc = 128 f32/thread.
// ---------------------------------------------------------------------------
__global__ __launch_bounds__(256) void gru_fused(const u16* __restrict__ agg,
                                                 const u16* __restrict__ h,
                                                 const u16* __restrict__ wcat,
                                                 const float* __restrict__ bih,
                                                 const float* __restrict__ bhh,
                                                 u16* __restrict__ hout) {
    __shared__ u16 S[20480];   // A[128][64]@0, W0@8192, W1@12288, W2@16384
    int tid = threadIdx.x;
    int lane = tid & 63, wave = tid >> 6;
    int wr = wave >> 1, wc = wave & 1;

    int bid = blockIdx.x;                 // grid 2512 = 8 xcd x 314
    int xcd = bid & 7;
    int s = bid >> 3;                     // 0..313
    int hi = (s >= 157) ? 1 : 0;
    int m0 = (s - hi * 157) * 128;
    int n0 = (xcd * 2 + hi) * 64;

    // staging maps (XOR swizzle): slot c (row=c>>3, sl=c&7), kc = sl^(row&7)
    int aoff[4], woff[2];
#pragma unroll
    for (int i = 0; i < 4; i++) {
        int c = tid + 256 * i;            // 0..1023: A rows 0..127
        int row = c >> 3, sl = c & 7;
        int kc = sl ^ (row & 7);
        aoff[i] = (m0 + row) * KP + kc * 8;
    }
#pragma unroll
    for (int i = 0; i < 2; i++) {
        int c = tid + 256 * i;            // 0..511: W rows 0..63
        int row = (c >> 3) & 63, sl = c & 7;
        int kc = sl ^ (row & 7);
        woff[i] = (n0 + row) * 2048 + kc * 8;
    }
    f32x4 aR[4][2] = {}, aZ[4][2] = {}, aN[4][2] = {}, aH[4][2] = {};
    int fr = lane & 15, q = lane >> 4, sw = fr & 7;

#define GRU_PHASE(APTR, K0W, AN)                                              \
    for (int kk = 0; kk < 16; kk++) {                                         \
        int ka = kk * 64, kw = K0W + kk * 64;                                 \
        _Pragma("unroll")                                                     \
        for (int i = 0; i < 4; i++)                                           \
            gl2lds16(APTR + aoff[i] + ka, &S[tid * 8 + 2048 * i]);            \
        _Pragma("unroll")                                                     \
        for (int i = 0; i < 2; i++) {                                         \
            gl2lds16(wcat + woff[i] + kw, &S[8192 + tid * 8 + 2048 * i]);     \
            gl2lds16(wcat + 2097152 + woff[i] + kw,                           \
                     &S[12288 + tid * 8 + 2048 * i]);                         \
            gl2lds16(wcat + 4194304 + woff[i] + kw,                           \
                     &S[16384 + tid * 8 + 2048 * i]);                         \
        }                                                                     \
        __syncthreads();                                                      \
        _Pragma("unroll")                                                     \
        for (int ks = 0; ks < 2; ks++) {                                      \
            int kx = ((ks * 4 + q) ^ sw) * 8;                                 \
            bf16x8 aa[4], w0[2], w1[2], w2[2];                                \
            _Pragma("unroll")                                                 \
            for (int i = 0; i < 4; i++)                                       \
                aa[i] = *(const bf16x8*)&S[(wr * 64 + i * 16 + fr) * 64 + kx];\
            _Pragma("unroll")                                                 \
            for (int j = 0; j < 2; j++) {                                     \
                int rb = (wc * 32 + j * 16 + fr) * 64 + kx;                   \
                w0[j] = *(const bf16x8*)&S[8192 + rb];                        \
                w1[j] = *(const bf16x8*)&S[12288 + rb];                       \
                w2[j] = *(const bf16x8*)&S[16384 + rb];                       \
            }                                                                 \
            _Pragma("unroll")                                                 \
            for (int i = 0; i < 4; i++)                                       \
                _Pragma("unroll")                                             \
                for (int j = 0; j < 2; j++) {                                 \
                    aR[i][j] = mfma16(aa[i], w0[j], aR[i][j]);                \
                    aZ[i][j] = mfma16(aa[i], w1[j], aZ[i][j]);                \
                    AN[i][j] = mfma16(aa[i], w2[j], AN[i][j]);                \
                }                                                             \
        }                                                                     \
        __syncthreads();                                                      \
    }

    GRU_PHASE(agg, 0, aN)      // k 0..1023:    agg vs w_ih -> r, z, i_n
    GRU_PHASE(h, 1024, aH)     // k 1024..2047: h   vs w_hh -> r, z, h_n
#undef GRU_PHASE

    int cc = lane & 15, r4 = q * 4;
#pragma unroll
    for (int j = 0; j < 2; j++) {
        int gn = n0 + wc * 32 + j * 16 + cc;
        if (gn >= DDIM) continue;
        float br  = bih[gn] + bhh[gn];
        float bz  = bih[1000 + gn] + bhh[1000 + gn];
        float bni = bih[2000 + gn];
        float bnh = bhh[2000 + gn];
#pragma unroll
        for (int i = 0; i < 4; i++)
#pragma unroll
            for (int r = 0; r < 4; r++) {
                int gm = m0 + wr * 64 + i * 16 + r4 + r;
                if (gm >= N_NODES) continue;
                float rg = sigmoidf_(aR[i][j][r] + br);
                float zg = sigmoidf_(aZ[i][j][r] + bz);
                float ng = tanhf(aN[i][j][r] + bni + rg * (aH[i][j][r] + bnh));
                size_t idx = (size_t)gm * KP + gn;
                float hp = b2f(h[idx]);
                hout[idx] = f2b((1.0f - zg) * ng + zg * hp);
            }
    }
}

// ---------------------------------------------------------------------------
// out[row] (fp32) = relu(h[row]) . fc_w + fc_b — one wave per row
// ---------------------------------------------------------------------------
__global__ __launch_bounds__(256) void fc_out(const u16* __restrict__ h,
                                              const float* __restrict__ fw,
                                              const float* __restrict__ fb,
                                              float* __restrict__ out) {
    int row = blockIdx.x * 4 + (threadIdx.x >> 6);
    int lane = threadIdx.x & 63;
    if (row >= N_NODES) return;
    float s = 0.0f;
    for (int i = 0; i < 4; i++) {
        int c = lane + 64 * i;
        if (c < 250) {
            uint2 v = *(const uint2*)(h + (size_t)row * KP + c * 4);
            float4 w = *(const float4*)(fw + c * 4);
            const u16* pv = (const u16*)&v;
            float h0 = b2f(pv[0]), h1 = b2f(pv[1]), h2 = b2f(pv[2]), h3 = b2f(pv[3]);
            s += (h0 > 0.0f ? h0 : 0.0f) * w.x;
            s += (h1 > 0.0f ? h1 : 0.0f) * w.y;
            s += (h2 > 0.0f ? h2 : 0.0f) * w.z;
            s += (h3 > 0.0f ? h3 : 0.0f) * w.w;
        }
    }
    for (int off = 32; off > 0; off >>= 1) s += __shfl_down(s, off, 64);
    if (lane == 0) out[row] = s + fb[0];
}

// ---------------------------------------------------------------------------
extern "C" void kernel_launch(void* const* d_in, const int* in_sizes, int n_in,
                              void* d_out, int out_size, void* d_ws, size_t ws_size,
                              hipStream_t stream) {
    const float* x   = (const float*)d_in[0];
    const int*   ei  = (const int*)d_in[1];
    const float* ew  = (const float*)d_in[2];
    const float* W   = (const float*)d_in[3];
    const float* wih = (const float*)d_in[4];
    const float* whh = (const float*)d_in[5];
    const float* bih = (const float*)d_in[6];
    const float* bhh = (const float*)d_in[7];
    const float* fw  = (const float*)d_in[8];
    const float* fb  = (const float*)d_in[9];
    float* out = (float*)d_out;

    // workspace (~144 MB)
    char* ws = (char*)d_ws;
    u16* xb   = (u16*)(ws);                    // [20000+][1024] bf16
    u16* bufA = (u16*)(ws + (size_t)SP);
    u16* bufB = (u16*)(ws + (size_t)2 * SP);   // agg
    u16* Wt   = (u16*)(ws + 123600000);        // 6.3 MB [3][1024][1024]
    u16* wcat = (u16*)(ws + 130000000);        // 12.6 MB [3][1024][2048]
    int* cnt  = (int*)(ws + 143000000);        // 80 KB
    int* cur  = (int*)(ws + 143100000);        // 80 KB
    int* ofs  = (int*)(ws + 143200000);        // 80 KB + 4
    int* bkt  = (int*)(ws + 143300096);        // 640 KB

    // one-time conversions + CSR build
    cvt_rows<<<N_NODES, 256, 0, stream>>>(x, xb);
    cvt_wcat<<<3000, 256, 0, stream>>>(wih, whh, wcat);
    transpose_w<<<dim3(32, 32, 3), dim3(32, 8), 0, stream>>>(W, Wt);
    hipMemsetAsync(cnt, 0, 80000, stream);
    hipMemsetAsync(cur, 0, 80000, stream);
    count_edges<<<625, 256, 0, stream>>>(ei, cnt);
    scan_offsets<<<1, 1024, 0, stream>>>(cnt, ofs);
    fill_buckets<<<625, 256, 0, stream>>>(ei, ofs, cur, bkt);

    // layer 0: h = xb; m -> bufA; agg -> bufB; h1 -> bufA (m dead)
    gemm_bt<<<1256, 256, 0, stream>>>(xb, Wt, bufA);
    node_agg<<<N_NODES, 256, 0, stream>>>(ei, ew, ofs, bkt, bufA, bufB);
    gru_fused<<<2512, 256, 0, stream>>>(bufB, xb, wcat, bih, bhh, bufA);

    // layer 1: h = bufA; m -> xb; agg -> bufB; h2 -> xb
    gemm_bt<<<1256, 256, 0, stream>>>(bufA, Wt + 1048576, xb);
    node_agg<<<N_NODES, 256, 0, stream>>>(ei, ew, ofs, bkt, xb, bufB);
    gru_fused<<<2512, 256, 0, stream>>>(bufB, bufA, wcat, bih, bhh, xb);

    // layer 2: h = xb; m -> bufA; agg -> bufB; h3 -> bufA
    gemm_bt<<<1256, 256, 0, stream>>>(xb, Wt + 2097152, bufA);
    node_agg<<<N_NODES, 256, 0, stream>>>(ei, ew, ofs, bkt, bufA, bufB);
    gru_fused<<<2512, 256, 0, stream>>>(bufB, xb, wcat, bih, bhh, bufA);

    // out = relu(h3) @ fc_w^T + fc_b
    fc_out<<<5000, 256, 0, stream>>>(bufA, fw, fb, out);
}